// Round 1
// baseline (10883.327 us; speedup 1.0000x reference)
//
#include <hip/hip_runtime.h>

// UCCAEncoder: 3x EdgeConv(max-aggr) + FFN + row gather.
// Factorization: z_e = U[dst] + V[src], U = h@(w1_top - w1_bot) + b1, V = h@w1_bot.
// Edge kernel fuses relu(z)@w2 with segment-max via uint-key atomicMax.
// All fp32 this round (baseline; bf16 MFMA planned once error headroom measured).

#define N_NODES 16384
#define EDGES   262144
#define HDIM    512
#define SEQ     2048

// ---------- Wd = w1_top - w1_bot ----------
__global__ __launch_bounds__(256) void prep_wd_kernel(
    const float* __restrict__ w1, float* __restrict__ Wd) {
    int idx = blockIdx.x * 256 + threadIdx.x;      // 262144 total
    Wd[idx] = w1[idx] - w1[idx + HDIM * HDIM];
}

// ---------- C[M,512] = A[M,512] @ W[512,512] (+bias) (relu?) ----------
// block = 32 rows x 512 cols, 256 threads, 8x8 acc/thread, K chunked by 128.
__global__ __launch_bounds__(256, 3) void gemm_rt_kernel(
    const float* __restrict__ A, const float* __restrict__ W,
    const float* __restrict__ bias, float* __restrict__ C, int relu) {
    __shared__ float rs[32][128];
    const int t  = threadIdx.x;
    const int r0 = blockIdx.x * 32;
    const int ty = t >> 6;          // 0..3 -> 8 rows each
    const int tx = t & 63;          // 0..63 -> 8 cols each
    const int c0 = tx * 8;
    float acc[8][8];
#pragma unroll
    for (int i = 0; i < 8; ++i)
#pragma unroll
        for (int j = 0; j < 8; ++j) acc[i][j] = 0.f;

    for (int kc = 0; kc < HDIM; kc += 128) {
#pragma unroll
        for (int it = 0; it < 4; ++it) {           // 1024 float4 over 256 threads
            int idx4 = it * 256 + t;
            int i = idx4 >> 5, c4 = idx4 & 31;
            float4 v = *(const float4*)(A + (size_t)(r0 + i) * HDIM + kc + c4 * 4);
            *(float4*)(&rs[i][c4 * 4]) = v;
        }
        __syncthreads();
        const float* wp = W + (size_t)kc * HDIM;
#pragma unroll 4
        for (int kk = 0; kk < 128; ++kk) {
            float a[8];
#pragma unroll
            for (int rr = 0; rr < 8; ++rr) a[rr] = rs[ty * 8 + rr][kk]; // wave-uniform broadcast
            const float* wrow = wp + kk * HDIM + c0;
            float4 w0 = *(const float4*)(wrow);
            float4 w1 = *(const float4*)(wrow + 4);
            float w[8] = {w0.x, w0.y, w0.z, w0.w, w1.x, w1.y, w1.z, w1.w};
#pragma unroll
            for (int rr = 0; rr < 8; ++rr)
#pragma unroll
                for (int j = 0; j < 8; ++j)
                    acc[rr][j] = fmaf(a[rr], w[j], acc[rr][j]);
        }
        __syncthreads();
    }
    float bv[8];
#pragma unroll
    for (int j = 0; j < 8; ++j) bv[j] = bias ? bias[c0 + j] : 0.f;
#pragma unroll
    for (int rr = 0; rr < 8; ++rr) {
        float* cp = C + (size_t)(r0 + ty * 8 + rr) * HDIM + c0;
        float o[8];
#pragma unroll
        for (int j = 0; j < 8; ++j) {
            float v = acc[rr][j] + bv[j];
            o[j] = relu ? fmaxf(v, 0.f) : v;
        }
        *(float4*)(cp)     = make_float4(o[0], o[1], o[2], o[3]);
        *(float4*)(cp + 4) = make_float4(o[4], o[5], o[6], o[7]);
    }
}

// ---------- fused edge MLP + segment max ----------
// 32 edges/block; m_e = relu(U[dst]+V[src]) @ w2 (b2 added at decode);
// atomicMax with monotone float->uint key; keys pre-zeroed (= -NaN, below all).
__global__ __launch_bounds__(256, 3) void edge_kernel(
    const float* __restrict__ U, const float* __restrict__ V,
    const float* __restrict__ W2, const int* __restrict__ src,
    const int* __restrict__ dst, unsigned int* __restrict__ K) {
    __shared__ float r[32][128];
    __shared__ int sdst[32], ssrc[32];
    const int t  = threadIdx.x;
    const int e0 = blockIdx.x * 32;
    if (t < 32) { sdst[t] = dst[e0 + t]; ssrc[t] = src[e0 + t]; }
    __syncthreads();
    const int ty = t >> 6;
    const int tx = t & 63;
    const int c0 = tx * 8;
    float acc[8][8];
#pragma unroll
    for (int i = 0; i < 8; ++i)
#pragma unroll
        for (int j = 0; j < 8; ++j) acc[i][j] = 0.f;

    for (int kc = 0; kc < HDIM; kc += 128) {
#pragma unroll
        for (int it = 0; it < 4; ++it) {
            int idx4 = it * 256 + t;
            int i = idx4 >> 5, c4 = idx4 & 31;
            const float4 u4 = *(const float4*)(U + (size_t)sdst[i] * HDIM + kc + c4 * 4);
            const float4 v4 = *(const float4*)(V + (size_t)ssrc[i] * HDIM + kc + c4 * 4);
            float4 z;
            z.x = fmaxf(u4.x + v4.x, 0.f);
            z.y = fmaxf(u4.y + v4.y, 0.f);
            z.z = fmaxf(u4.z + v4.z, 0.f);
            z.w = fmaxf(u4.w + v4.w, 0.f);
            *(float4*)(&r[i][c4 * 4]) = z;
        }
        __syncthreads();
        const float* wp = W2 + (size_t)kc * HDIM;
#pragma unroll 4
        for (int kk = 0; kk < 128; ++kk) {
            float a[8];
#pragma unroll
            for (int rr = 0; rr < 8; ++rr) a[rr] = r[ty * 8 + rr][kk]; // wave-uniform broadcast
            const float* wrow = wp + kk * HDIM + c0;
            float4 w0 = *(const float4*)(wrow);
            float4 w1 = *(const float4*)(wrow + 4);
            float w[8] = {w0.x, w0.y, w0.z, w0.w, w1.x, w1.y, w1.z, w1.w};
#pragma unroll
            for (int rr = 0; rr < 8; ++rr)
#pragma unroll
                for (int j = 0; j < 8; ++j)
                    acc[rr][j] = fmaf(a[rr], w[j], acc[rr][j]);
        }
        __syncthreads();
    }
#pragma unroll
    for (int rr = 0; rr < 8; ++rr) {
        unsigned int* kp = K + (size_t)sdst[ty * 8 + rr] * HDIM + c0;
#pragma unroll
        for (int j = 0; j < 8; ++j) {
            unsigned int b   = __float_as_uint(acc[rr][j]);
            unsigned int key = (b & 0x80000000u) ? ~b : (b | 0x80000000u);
            atomicMax(kp + j, key);
        }
    }
}

// ---------- decode keys -> h = max(max_e(m)+b2, 0); key==0 (empty) -> 0 ----------
__global__ __launch_bounds__(256) void decode_kernel(
    const unsigned int* __restrict__ K, const float* __restrict__ b2,
    float* __restrict__ hout) {
    int idx = blockIdx.x * 256 + threadIdx.x;      // N*H total
    unsigned int k = K[idx];
    int c = idx & (HDIM - 1);
    float v = 0.f;
    if (k != 0u) {
        unsigned int b = (k & 0x80000000u) ? (k ^ 0x80000000u) : ~k;
        v = __uint_as_float(b) + b2[c];
    }
    hout[idx] = fmaxf(v, 0.f);
}

// ---------- gather selected rows: hg[b*SEL+j] = h[b*S + sel[b*SEL+j]] ----------
__global__ __launch_bounds__(256) void gather_kernel(
    const float* __restrict__ h, const int* __restrict__ sel,
    float* __restrict__ hg) {
    int idx = blockIdx.x * 256 + threadIdx.x;      // 4096*512 total
    int row = idx >> 9;                            // 0..4095
    int c   = idx & (HDIM - 1);
    int b   = row >> 9;                            // SEL = 512
    int s   = sel[row];
    hg[idx] = h[((size_t)(b * SEQ + s) << 9) + c];
}

extern "C" void kernel_launch(void* const* d_in, const int* in_sizes, int n_in,
                              void* d_out, int out_size, void* d_ws, size_t ws_size,
                              hipStream_t stream) {
    const float* x    = (const float*)d_in[0];
    const int*   ei   = (const int*)d_in[1];
    const int*   sel  = (const int*)d_in[2];
    const int*   src  = ei;            // edge_index[0] = source
    const int*   dst  = ei + EDGES;    // edge_index[1] = target
    const float* cw1[3] = {(const float*)d_in[4],  (const float*)d_in[8],  (const float*)d_in[12]};
    const float* cb1[3] = {(const float*)d_in[5],  (const float*)d_in[9],  (const float*)d_in[13]};
    const float* cw2[3] = {(const float*)d_in[6],  (const float*)d_in[10], (const float*)d_in[14]};
    const float* cb2[3] = {(const float*)d_in[7],  (const float*)d_in[11], (const float*)d_in[15]};
    const float* fw1 = (const float*)d_in[16];
    const float* fb1 = (const float*)d_in[17];
    const float* fw2 = (const float*)d_in[18];
    const float* fb2 = (const float*)d_in[19];
    float* out = (float*)d_out;

    const size_t BUF = (size_t)N_NODES * HDIM * sizeof(float);   // 32 MB
    char* wsb   = (char*)d_ws;
    float* U    = (float*)(wsb);
    float* V    = (float*)(wsb + BUF);
    float* bufA = (float*)(wsb + 2 * BUF);
    float* bufB = (float*)(wsb + 3 * BUF);
    float* hg   = U;   // dead after layer 2
    float* t1   = V;

    for (int l = 0; l < 3; ++l) {
        const float* hin = (l == 0) ? x : ((l == 1) ? bufA : bufB);
        float* keyf = (l == 1) ? bufB : bufA;     // L0->A, L1->B, L2->A
        unsigned int* keys = (unsigned int*)keyf;
        float* Wd = keyf;                          // scratch inside keys buf (dead until memset)

        prep_wd_kernel<<<EDGES / 256, 256, 0, stream>>>(cw1[l], Wd);
        gemm_rt_kernel<<<N_NODES / 32, 256, 0, stream>>>(hin, Wd, cb1[l], U, 0);
        gemm_rt_kernel<<<N_NODES / 32, 256, 0, stream>>>(hin, cw1[l] + HDIM * HDIM, nullptr, V, 0);
        hipMemsetAsync(keys, 0, BUF, stream);
        edge_kernel<<<EDGES / 32, 256, 0, stream>>>(U, V, cw2[l], src, dst, keys);
        decode_kernel<<<N_NODES * HDIM / 256, 256, 0, stream>>>(keys, cb2[l], keyf);
    }

    float* h3 = bufA;
    gather_kernel<<<(8 * 512 * HDIM) / 256, 256, 0, stream>>>(h3, sel, hg);
    gemm_rt_kernel<<<4096 / 32, 256, 0, stream>>>(hg, fw1, fb1, t1, 1);
    gemm_rt_kernel<<<4096 / 32, 256, 0, stream>>>(t1, fw2, fb2, out, 0);
}

// Round 2
// 2239.108 us; speedup vs baseline: 4.8606x; 4.8606x over previous
//
#include <hip/hip_runtime.h>
#include <hip/hip_bf16.h>

// UCCAEncoder: 3x EdgeConv(max) + FFN + gather.
// R2: conv GEMMs on bf16 MFMA (16x16x32), m97-style 128x128 tiles.
//   z_e = relu(U[dst]+V[src]),  U = h@(w1a-w1b)+b1, V = h@w1b   (bf16)
//   edge kernel: A-tile = gathered z (VALU pack), B-tile = W2^T via global_load_lds,
//   epilogue = atomicMax(uint-key) segment max. FFN kept fp32 for error headroom.

#define N_NODES 16384
#define EDGES   262144
#define HDIM    512
#define SEQ     2048

typedef __attribute__((ext_vector_type(8))) short short8;
typedef __attribute__((ext_vector_type(4))) float f32x4;

__device__ __forceinline__ void gld16(const void* g, void* l) {
    __builtin_amdgcn_global_load_lds(
        (const __attribute__((address_space(1))) void*)g,
        (__attribute__((address_space(3))) void*)l, 16, 0, 0);
}

__device__ __forceinline__ unsigned short f2b(float f) {   // fp32 -> bf16 RNE
    unsigned int x = __float_as_uint(f);
    return (unsigned short)((x + 0x7fffu + ((x >> 16) & 1u)) >> 16);
}
__device__ __forceinline__ float blo(unsigned int u) { return __uint_as_float(u << 16); }
__device__ __forceinline__ float bhi(unsigned int u) { return __uint_as_float(u & 0xffff0000u); }
__device__ __forceinline__ unsigned int zpack(unsigned int u, unsigned int v) {
    float zl = fmaxf(blo(u) + blo(v), 0.f);
    float zh = fmaxf(bhi(u) + bhi(v), 0.f);
    return (unsigned int)f2b(zl) | ((unsigned int)f2b(zh) << 16);
}
// LDS k-seg swizzle: physical slot = logical_seg ^ ((row>>1)&3)  (breaks 8-way conflict)
__device__ __forceinline__ short8 frag_ld(const short* S, int row, int q) {
    int p = q ^ ((row >> 1) & 3);
    return *(const short8*)(S + row * 32 + p * 8);
}

// ---------- weights prep: transpose 512x512 to [n][k] bf16 (z=0 Wd, 1 w1b, 2 W2) ----------
__global__ __launch_bounds__(256) void prep_weights_kernel(
    const float* __restrict__ w1, const float* __restrict__ w2,
    short* __restrict__ WdT, short* __restrict__ w1bT, short* __restrict__ W2T) {
    __shared__ float tile[32][33];
    const int which = blockIdx.z;
    const int k0 = blockIdx.x * 32, n0 = blockIdx.y * 32;
    const int tx = threadIdx.x, ty = threadIdx.y;      // 32 x 8
#pragma unroll
    for (int i = 0; i < 4; ++i) {
        int k = k0 + ty + i * 8, n = n0 + tx;
        float v;
        if (which == 0)      v = w1[k * 512 + n] - w1[(k + 512) * 512 + n];
        else if (which == 1) v = w1[(k + 512) * 512 + n];
        else                 v = w2[k * 512 + n];
        tile[ty + i * 8][tx] = v;
    }
    __syncthreads();
    short* out = which == 0 ? WdT : (which == 1 ? w1bT : W2T);
#pragma unroll
    for (int i = 0; i < 4; ++i) {
        int n = n0 + ty + i * 8, k = k0 + tx;
        out[(size_t)n * 512 + k] = (short)f2b(tile[tx][ty + i * 8]);
    }
}

// ---------- x -> bf16 ----------
__global__ __launch_bounds__(256) void cvt_bf16_kernel(
    const float* __restrict__ x, short* __restrict__ xb) {
    int idx = blockIdx.x * 256 + threadIdx.x;          // per 4 elements
    float4 v = ((const float4*)x)[idx];
    uint2 o;
    o.x = (unsigned int)f2b(v.x) | ((unsigned int)f2b(v.y) << 16);
    o.y = (unsigned int)f2b(v.z) | ((unsigned int)f2b(v.w) << 16);
    ((uint2*)xb)[idx] = o;
}

// ---------- node GEMM: C[M,512] = bf16( A[M,512] @ Wt^T + bias ), all bf16, fp32 acc ----------
// 128x128 tile, 256 thr = 4 waves (2x2 of 64x64), Bk=32, both tiles via global_load_lds.
__global__ __launch_bounds__(256) void node_gemm_kernel(
    const short* __restrict__ A, const short* __restrict__ Wt,
    const float* __restrict__ bias, short* __restrict__ C) {
    __shared__ short As[128 * 32];
    __shared__ short Bs[128 * 32];
    const int t = threadIdx.x;
    const int m0 = blockIdx.x * 128, n0 = blockIdx.y * 128;
    const int w = t >> 6, l = t & 63;
    const int wm = (w & 1) * 64, wn = (w >> 1) * 64;
    f32x4 acc[4][4] = {};

    for (int kc = 0; kc < HDIM; kc += 32) {
#pragma unroll
        for (int it = 0; it < 2; ++it) {
            int lin = it * 256 + t;
            int row = lin >> 2, p = lin & 3;
            int q = p ^ ((row >> 1) & 3);              // logical k-seg for this slot
            gld16(A  + (size_t)(m0 + row) * HDIM + kc + q * 8, As + lin * 8);
            gld16(Wt + (size_t)(n0 + row) * HDIM + kc + q * 8, Bs + lin * 8);
        }
        __syncthreads();
        short8 a[4], b[4];
#pragma unroll
        for (int mt = 0; mt < 4; ++mt) a[mt] = frag_ld(As, wm + mt * 16 + (l & 15), l >> 4);
#pragma unroll
        for (int nt = 0; nt < 4; ++nt) b[nt] = frag_ld(Bs, wn + nt * 16 + (l & 15), l >> 4);
#pragma unroll
        for (int mt = 0; mt < 4; ++mt)
#pragma unroll
            for (int nt = 0; nt < 4; ++nt)
                acc[mt][nt] = __builtin_amdgcn_mfma_f32_16x16x32_bf16(a[mt], b[nt], acc[mt][nt], 0, 0, 0);
        __syncthreads();
    }
#pragma unroll
    for (int mt = 0; mt < 4; ++mt) {
        int m = m0 + wm + mt * 16 + (l >> 4) * 4;
#pragma unroll
        for (int nt = 0; nt < 4; ++nt) {
            int n = n0 + wn + nt * 16 + (l & 15);
            float bv = bias ? bias[n] : 0.f;
#pragma unroll
            for (int r = 0; r < 4; ++r)
                C[(size_t)(m + r) * HDIM + n] = (short)f2b(acc[mt][nt][r] + bv);
        }
    }
}

// ---------- edge GEMM: m_e = relu(U[dst_e]+V[src_e]) @ W2, fused segment-max ----------
__global__ __launch_bounds__(256) void edge_mfma_kernel(
    const short* __restrict__ U, const short* __restrict__ V,
    const short* __restrict__ Wt, const int* __restrict__ src,
    const int* __restrict__ dst, unsigned int* __restrict__ K) {
    __shared__ short As[128 * 32];
    __shared__ short Bs[128 * 32];
    __shared__ int sdst[128], ssrc[128];
    const int t = threadIdx.x;
    const int e0 = blockIdx.x * 128, n0 = blockIdx.y * 128;
    if (t < 128) { sdst[t] = dst[e0 + t]; ssrc[t] = src[e0 + t]; }
    __syncthreads();
    const int w = t >> 6, l = t & 63;
    const int wm = (w & 1) * 64, wn = (w >> 1) * 64;
    const int arow = t >> 1, ahalf = t & 1;
    const short* up = U + (((size_t)sdst[arow]) << 9) + ahalf * 16;
    const short* vp = V + (((size_t)ssrc[arow]) << 9) + ahalf * 16;
    const int f = (arow >> 1) & 3;                     // swizzle for this row
    unsigned int* As_u = (unsigned int*)As;
    f32x4 acc[4][4] = {};

    for (int kc = 0; kc < HDIM; kc += 32) {
        // B tile via async LDS load
#pragma unroll
        for (int it = 0; it < 2; ++it) {
            int lin = it * 256 + t;
            int row = lin >> 2, p = lin & 3;
            int q = p ^ ((row >> 1) & 3);
            gld16(Wt + (size_t)(n0 + row) * HDIM + kc + q * 8, Bs + lin * 8);
        }
        // A tile: gather 16 els of U,V -> relu(add) -> bf16 pack -> LDS (swizzled slots)
        {
            const uint4 u0 = *(const uint4*)(up + kc);
            const uint4 u1 = *(const uint4*)(up + kc + 8);
            const uint4 v0 = *(const uint4*)(vp + kc);
            const uint4 v1 = *(const uint4*)(vp + kc + 8);
            uint4 z0, z1;
            z0.x = zpack(u0.x, v0.x); z0.y = zpack(u0.y, v0.y);
            z0.z = zpack(u0.z, v0.z); z0.w = zpack(u0.w, v0.w);
            z1.x = zpack(u1.x, v1.x); z1.y = zpack(u1.y, v1.y);
            z1.z = zpack(u1.z, v1.z); z1.w = zpack(u1.w, v1.w);
            int p0 = (2 * ahalf) ^ f, p1 = (2 * ahalf + 1) ^ f;
            *(uint4*)(As_u + arow * 16 + p0 * 4) = z0;
            *(uint4*)(As_u + arow * 16 + p1 * 4) = z1;
        }
        __syncthreads();
        short8 a[4], b[4];
#pragma unroll
        for (int mt = 0; mt < 4; ++mt) a[mt] = frag_ld(As, wm + mt * 16 + (l & 15), l >> 4);
#pragma unroll
        for (int nt = 0; nt < 4; ++nt) b[nt] = frag_ld(Bs, wn + nt * 16 + (l & 15), l >> 4);
#pragma unroll
        for (int mt = 0; mt < 4; ++mt)
#pragma unroll
            for (int nt = 0; nt < 4; ++nt)
                acc[mt][nt] = __builtin_amdgcn_mfma_f32_16x16x32_bf16(a[mt], b[nt], acc[mt][nt], 0, 0, 0);
        __syncthreads();
    }
    // epilogue: segment-max via monotone-key atomicMax
#pragma unroll
    for (int mt = 0; mt < 4; ++mt) {
        int er = wm + mt * 16 + (l >> 4) * 4;
#pragma unroll
        for (int r = 0; r < 4; ++r) {
            unsigned int* kp = K + (((size_t)sdst[er + r]) << 9) + n0 + wn;
#pragma unroll
            for (int nt = 0; nt < 4; ++nt) {
                unsigned int b = __float_as_uint(acc[mt][nt][r]);
                unsigned int key = ((int)b < 0) ? ~b : (b | 0x80000000u);
                atomicMax(kp + nt * 16 + (l & 15), key);
            }
        }
    }
}

// ---------- decode keys -> h (fp32 + bf16); key==0 (empty) -> 0 ----------
__global__ __launch_bounds__(256) void decode_kernel(
    const unsigned int* __restrict__ K, const float* __restrict__ b2,
    float* __restrict__ hf, short* __restrict__ hb) {
    int idx = blockIdx.x * 256 + threadIdx.x;
    unsigned int k = K[idx];
    int c = idx & (HDIM - 1);
    float v = 0.f;
    if (k != 0u) {
        unsigned int b = (k & 0x80000000u) ? (k ^ 0x80000000u) : ~k;
        v = __uint_as_float(b) + b2[c];
    }
    v = fmaxf(v, 0.f);
    hf[idx] = v;
    hb[idx] = (short)f2b(v);
}

// ---------- fp32 FFN GEMM (round-1 kernel, kept for error headroom) ----------
__global__ __launch_bounds__(256, 3) void gemm_rt_kernel(
    const float* __restrict__ A, const float* __restrict__ W,
    const float* __restrict__ bias, float* __restrict__ C, int relu) {
    __shared__ float rs[32][128];
    const int t = threadIdx.x;
    const int r0 = blockIdx.x * 32;
    const int ty = t >> 6, tx = t & 63;
    const int c0 = tx * 8;
    float acc[8][8];
#pragma unroll
    for (int i = 0; i < 8; ++i)
#pragma unroll
        for (int j = 0; j < 8; ++j) acc[i][j] = 0.f;
    for (int kc = 0; kc < HDIM; kc += 128) {
#pragma unroll
        for (int it = 0; it < 4; ++it) {
            int idx4 = it * 256 + t;
            int i = idx4 >> 5, c4 = idx4 & 31;
            float4 v = *(const float4*)(A + (size_t)(r0 + i) * HDIM + kc + c4 * 4);
            *(float4*)(&rs[i][c4 * 4]) = v;
        }
        __syncthreads();
        const float* wp = W + (size_t)kc * HDIM;
#pragma unroll 4
        for (int kk = 0; kk < 128; ++kk) {
            float a[8];
#pragma unroll
            for (int rr = 0; rr < 8; ++rr) a[rr] = rs[ty * 8 + rr][kk];
            const float* wrow = wp + kk * HDIM + c0;
            float4 w0 = *(const float4*)(wrow);
            float4 w1 = *(const float4*)(wrow + 4);
            float wv[8] = {w0.x, w0.y, w0.z, w0.w, w1.x, w1.y, w1.z, w1.w};
#pragma unroll
            for (int rr = 0; rr < 8; ++rr)
#pragma unroll
                for (int j = 0; j < 8; ++j)
                    acc[rr][j] = fmaf(a[rr], wv[j], acc[rr][j]);
        }
        __syncthreads();
    }
#pragma unroll
    for (int rr = 0; rr < 8; ++rr) {
        float* cp = C + (size_t)(r0 + ty * 8 + rr) * HDIM + c0;
        float o[8];
#pragma unroll
        for (int j = 0; j < 8; ++j) {
            float v = acc[rr][j] + bias[c0 + j];
            o[j] = relu ? fmaxf(v, 0.f) : v;
        }
        *(float4*)(cp)     = make_float4(o[0], o[1], o[2], o[3]);
        *(float4*)(cp + 4) = make_float4(o[4], o[5], o[6], o[7]);
    }
}

// ---------- gather selected rows ----------
__global__ __launch_bounds__(256) void gather_kernel(
    const float* __restrict__ h, const int* __restrict__ sel,
    float* __restrict__ hg) {
    int idx = blockIdx.x * 256 + threadIdx.x;          // 4096*512
    int row = idx >> 9, c = idx & (HDIM - 1);
    int b = row >> 9;                                  // SEL = 512
    int s = sel[row];
    hg[idx] = h[((size_t)(b * SEQ + s) << 9) + c];
}

extern "C" void kernel_launch(void* const* d_in, const int* in_sizes, int n_in,
                              void* d_out, int out_size, void* d_ws, size_t ws_size,
                              hipStream_t stream) {
    const float* x   = (const float*)d_in[0];
    const int*   ei  = (const int*)d_in[1];
    const int*   sel = (const int*)d_in[2];
    const int*   src = ei;
    const int*   dst = ei + EDGES;
    const float* cw1[3] = {(const float*)d_in[4],  (const float*)d_in[8],  (const float*)d_in[12]};
    const float* cb1[3] = {(const float*)d_in[5],  (const float*)d_in[9],  (const float*)d_in[13]};
    const float* cw2[3] = {(const float*)d_in[6],  (const float*)d_in[10], (const float*)d_in[14]};
    const float* cb2[3] = {(const float*)d_in[7],  (const float*)d_in[11], (const float*)d_in[15]};
    const float* fw1 = (const float*)d_in[16];
    const float* fb1 = (const float*)d_in[17];
    const float* fw2 = (const float*)d_in[18];
    const float* fb2 = (const float*)d_in[19];
    float* out = (float*)d_out;

    const size_t MB = 1024 * 1024;
    char* p = (char*)d_ws;
    float*        hf   = (float*)p;                    // 32 MB
    unsigned int* keys = (unsigned int*)(p + 32 * MB); // 32 MB
    short*        U    = (short*)(p + 64 * MB);        // 16 MB
    short*        V    = (short*)(p + 80 * MB);        // 16 MB
    short*        hb   = (short*)(p + 96 * MB);        // 16 MB (x_bf16 first)
    short*        WdT  = (short*)(p + 112 * MB);       // 3 x 0.5 MB
    short*        w1bT = WdT + 512 * 512;
    short*        W2T  = w1bT + 512 * 512;
    float*        hg   = (float*)(p + 64 * MB);        // alias U (dead by then)
    float*        t1   = (float*)(p + 80 * MB);        // alias V

    cvt_bf16_kernel<<<8192, 256, 0, stream>>>(x, hb);

    for (int l = 0; l < 3; ++l) {
        prep_weights_kernel<<<dim3(16, 16, 3), dim3(32, 8), 0, stream>>>(
            cw1[l], cw2[l], WdT, w1bT, W2T);
        node_gemm_kernel<<<dim3(128, 4), 256, 0, stream>>>(hb, WdT, cb1[l], U);
        node_gemm_kernel<<<dim3(128, 4), 256, 0, stream>>>(hb, w1bT, nullptr, V);
        hipMemsetAsync(keys, 0, 32 * MB, stream);
        edge_mfma_kernel<<<dim3(2048, 4), 256, 0, stream>>>(U, V, W2T, src, dst, keys);
        decode_kernel<<<(N_NODES * HDIM) / 256, 256, 0, stream>>>(keys, cb2[l], hf, hb);
    }

    gather_kernel<<<(8 * 512 * HDIM) / 256, 256, 0, stream>>>(hf, sel, hg);
    gemm_rt_kernel<<<4096 / 32, 256, 0, stream>>>(hg, fw1, fb1, t1, 1);
    gemm_rt_kernel<<<4096 / 32, 256, 0, stream>>>(t1, fw2, fb2, out, 0);
}

// Round 3
// 1491.564 us; speedup vs baseline: 7.2966x; 1.5012x over previous
//
#include <hip/hip_runtime.h>
#include <hip/hip_bf16.h>

// UCCAEncoder: 3x EdgeConv(max) + FFN + gather. R3:
//  - counting-sort edges by dst (once): L1-local U gathers + run-compressed atomics
//  - fused U/V node GEMM (one A pass, 2 B mats)
//  - FFN on bf16 MFMA; bf16-only h path
// z_e = relu(U[dst]+V[src]), U = h@(w1a-w1b)+b1, V = h@w1b; edge GEMM fuses
// relu(z)@W2 with segment-max via monotone-uint atomicMax.

#define N_NODES 16384
#define EDGES   262144
#define HDIM    512
#define SEQ     2048

typedef __attribute__((ext_vector_type(8))) short short8;
typedef __attribute__((ext_vector_type(4))) float f32x4;

__device__ __forceinline__ void gld16(const void* g, void* l) {
    __builtin_amdgcn_global_load_lds(
        (const __attribute__((address_space(1))) void*)g,
        (__attribute__((address_space(3))) void*)l, 16, 0, 0);
}
__device__ __forceinline__ unsigned short f2b(float f) {   // fp32 -> bf16 RNE
    unsigned int x = __float_as_uint(f);
    return (unsigned short)((x + 0x7fffu + ((x >> 16) & 1u)) >> 16);
}
__device__ __forceinline__ float blo(unsigned int u) { return __uint_as_float(u << 16); }
__device__ __forceinline__ float bhi(unsigned int u) { return __uint_as_float(u & 0xffff0000u); }
__device__ __forceinline__ unsigned int zpack(unsigned int u, unsigned int v) {
    float zl = fmaxf(blo(u) + blo(v), 0.f);
    float zh = fmaxf(bhi(u) + bhi(v), 0.f);
    return (unsigned int)f2b(zl) | ((unsigned int)f2b(zh) << 16);
}
// LDS k-seg swizzle: physical slot = logical_seg ^ ((row>>1)&3)
__device__ __forceinline__ short8 frag_ld(const short* S, int row, int q) {
    int p = q ^ ((row >> 1) & 3);
    return *(const short8*)(S + row * 32 + p * 8);
}
// stage 128 rows x 32 k (bf16) via global_load_lds, swizzled slots
__device__ __forceinline__ void stage_tile(const short* G, int kc, short* S, int t) {
#pragma unroll
    for (int it = 0; it < 2; ++it) {
        int lin = it * 256 + t;
        int row = lin >> 2, p = lin & 3;
        int q = p ^ ((row >> 1) & 3);
        gld16(G + (size_t)row * HDIM + kc + q * 8, S + lin * 8);
    }
}
__device__ __forceinline__ void mfma_tile(const short* As, const short* Bs,
                                          int wm, int wn, int l, f32x4 acc[4][4]) {
    short8 a[4], b[4];
#pragma unroll
    for (int mt = 0; mt < 4; ++mt) a[mt] = frag_ld(As, wm + mt * 16 + (l & 15), l >> 4);
#pragma unroll
    for (int nt = 0; nt < 4; ++nt) b[nt] = frag_ld(Bs, wn + nt * 16 + (l & 15), l >> 4);
#pragma unroll
    for (int mt = 0; mt < 4; ++mt)
#pragma unroll
        for (int nt = 0; nt < 4; ++nt)
            acc[mt][nt] = __builtin_amdgcn_mfma_f32_16x16x32_bf16(a[mt], b[nt], acc[mt][nt], 0, 0, 0);
}

// ================= edge sort (counting sort by dst) =================
__global__ __launch_bounds__(256) void hist_kernel(
    const int* __restrict__ dst, int* __restrict__ hist) {
    int idx = blockIdx.x * 256 + threadIdx.x;
    atomicAdd(&hist[dst[idx]], 1);
}
__global__ __launch_bounds__(256) void scan_kernel(
    const int* __restrict__ hist, int* __restrict__ cursor) {
    __shared__ int part[256];
    const int t = threadIdx.x, base = t * 64;
    int sum = 0;
    for (int i = 0; i < 64; ++i) sum += hist[base + i];
    part[t] = sum;
    __syncthreads();
    int run = 0;
    for (int i = 0; i < t; ++i) run += part[i];
    for (int i = 0; i < 64; ++i) {
        int h = hist[base + i];
        cursor[base + i] = run;
        run += h;
    }
}
__global__ __launch_bounds__(256) void scatter_kernel(
    const int* __restrict__ dst, const int* __restrict__ src,
    int* __restrict__ cursor, int* __restrict__ dstS, int* __restrict__ srcS) {
    int idx = blockIdx.x * 256 + threadIdx.x;
    int d = dst[idx];
    int p = atomicAdd(&cursor[d], 1);
    dstS[p] = d;
    srcS[p] = src[idx];
}

// ================= weights / input prep =================
// conv trio: z=0 Wd=w1a-w1b, z=1 w1b, z=2 w2 -> [n][k] bf16
__global__ __launch_bounds__(256) void prep_weights_kernel(
    const float* __restrict__ w1, const float* __restrict__ w2,
    short* __restrict__ WdT, short* __restrict__ w1bT, short* __restrict__ W2T) {
    __shared__ float tile[32][33];
    const int which = blockIdx.z;
    const int k0 = blockIdx.x * 32, n0 = blockIdx.y * 32;
    const int tx = threadIdx.x, ty = threadIdx.y;
#pragma unroll
    for (int i = 0; i < 4; ++i) {
        int k = k0 + ty + i * 8, n = n0 + tx;
        float v;
        if (which == 0)      v = w1[k * 512 + n] - w1[(k + 512) * 512 + n];
        else if (which == 1) v = w1[(k + 512) * 512 + n];
        else                 v = w2[k * 512 + n];
        tile[ty + i * 8][tx] = v;
    }
    __syncthreads();
    short* out = which == 0 ? WdT : (which == 1 ? w1bT : W2T);
#pragma unroll
    for (int i = 0; i < 4; ++i) {
        int n = n0 + ty + i * 8, k = k0 + tx;
        out[(size_t)n * 512 + k] = (short)f2b(tile[tx][ty + i * 8]);
    }
}
// FFN mats: z=0 fw1, z=1 fw2
__global__ __launch_bounds__(256) void tr_kernel(
    const float* __restrict__ W1, const float* __restrict__ W2,
    short* __restrict__ T1, short* __restrict__ T2) {
    __shared__ float tile[32][33];
    const float* W = blockIdx.z ? W2 : W1;
    short* T = blockIdx.z ? T2 : T1;
    const int k0 = blockIdx.x * 32, n0 = blockIdx.y * 32;
    const int tx = threadIdx.x, ty = threadIdx.y;
#pragma unroll
    for (int i = 0; i < 4; ++i)
        tile[ty + i * 8][tx] = W[(k0 + ty + i * 8) * 512 + n0 + tx];
    __syncthreads();
#pragma unroll
    for (int i = 0; i < 4; ++i)
        T[(size_t)(n0 + ty + i * 8) * 512 + k0 + tx] = (short)f2b(tile[tx][ty + i * 8]);
}
__global__ __launch_bounds__(256) void cvt_bf16_kernel(
    const float* __restrict__ x, short* __restrict__ xb) {
    int idx = blockIdx.x * 256 + threadIdx.x;
    float4 v = ((const float4*)x)[idx];
    uint2 o;
    o.x = (unsigned int)f2b(v.x) | ((unsigned int)f2b(v.y) << 16);
    o.y = (unsigned int)f2b(v.z) | ((unsigned int)f2b(v.w) << 16);
    ((uint2*)xb)[idx] = o;
}

// ================= fused U/V node GEMM =================
// grid (128, 8): y<4 -> U = h@WdT^T + b1 ; y>=4 -> V = h@w1bT^T
__global__ __launch_bounds__(256) void node_gemm_uv_kernel(
    const short* __restrict__ A, const short* __restrict__ WdT,
    const short* __restrict__ w1bT, const float* __restrict__ b1,
    short* __restrict__ U, short* __restrict__ V) {
    __shared__ short As[128 * 32];
    __shared__ short Bs[128 * 32];
    const int t = threadIdx.x;
    const int by = blockIdx.y;
    const short* Wt = (by < 4) ? WdT : w1bT;
    short* C = (by < 4) ? U : V;
    const float* bias = (by < 4) ? b1 : nullptr;
    const int m0 = blockIdx.x * 128, n0 = (by & 3) * 128;
    const int w = t >> 6, l = t & 63;
    const int wm = (w & 1) * 64, wn = (w >> 1) * 64;
    f32x4 acc[4][4] = {};
    for (int kc = 0; kc < HDIM; kc += 32) {
        stage_tile(A + (size_t)m0 * HDIM, kc, As, t);
        stage_tile(Wt + (size_t)n0 * HDIM, kc, Bs, t);
        __syncthreads();
        mfma_tile(As, Bs, wm, wn, l, acc);
        __syncthreads();
    }
#pragma unroll
    for (int mt = 0; mt < 4; ++mt) {
        int m = m0 + wm + mt * 16 + (l >> 4) * 4;
#pragma unroll
        for (int nt = 0; nt < 4; ++nt) {
            int n = n0 + wn + nt * 16 + (l & 15);
            float bv = bias ? bias[n] : 0.f;
#pragma unroll
            for (int r = 0; r < 4; ++r)
                C[(size_t)(m + r) * HDIM + n] = (short)f2b(acc[mt][nt][r] + bv);
        }
    }
}

// ================= edge GEMM (sorted) + fused segment-max =================
__device__ __forceinline__ void kflush(unsigned int* K, int d, int col, float m) {
    unsigned int b = __float_as_uint(m);
    unsigned int key = ((int)b < 0) ? ~b : (b | 0x80000000u);
    atomicMax(K + (((size_t)d) << 9) + col, key);
}
__global__ __launch_bounds__(256) void edge_mfma_kernel(
    const short* __restrict__ U, const short* __restrict__ V,
    const short* __restrict__ Wt, const int* __restrict__ srcS,
    const int* __restrict__ dstS, unsigned int* __restrict__ K) {
    __shared__ short As[128 * 32];
    __shared__ short Bs[128 * 32];
    __shared__ int sdst[128], ssrc[128];
    const int t = threadIdx.x;
    const int e0 = blockIdx.x * 128, n0 = blockIdx.y * 128;
    if (t < 128) { sdst[t] = dstS[e0 + t]; ssrc[t] = srcS[e0 + t]; }
    __syncthreads();
    const int w = t >> 6, l = t & 63;
    const int wm = (w & 1) * 64, wn = (w >> 1) * 64;
    const int arow = t >> 1, ahalf = t & 1;
    const short* up = U + (((size_t)sdst[arow]) << 9) + ahalf * 16;
    const short* vp = V + (((size_t)ssrc[arow]) << 9) + ahalf * 16;
    const int f = (arow >> 1) & 3;
    unsigned int* As_u = (unsigned int*)As;
    f32x4 acc[4][4] = {};

    for (int kc = 0; kc < HDIM; kc += 32) {
        stage_tile(Wt + (size_t)n0 * HDIM, kc, Bs, t);
        {   // A tile: gather 16 els of U,V -> relu(add) -> bf16 -> LDS (swizzled)
            const uint4 u0 = *(const uint4*)(up + kc);
            const uint4 u1 = *(const uint4*)(up + kc + 8);
            const uint4 v0 = *(const uint4*)(vp + kc);
            const uint4 v1 = *(const uint4*)(vp + kc + 8);
            uint4 z0, z1;
            z0.x = zpack(u0.x, v0.x); z0.y = zpack(u0.y, v0.y);
            z0.z = zpack(u0.z, v0.z); z0.w = zpack(u0.w, v0.w);
            z1.x = zpack(u1.x, v1.x); z1.y = zpack(u1.y, v1.y);
            z1.z = zpack(u1.z, v1.z); z1.w = zpack(u1.w, v1.w);
            int p0 = (2 * ahalf) ^ f, p1 = (2 * ahalf + 1) ^ f;
            *(uint4*)(As_u + arow * 16 + p0 * 4) = z0;
            *(uint4*)(As_u + arow * 16 + p1 * 4) = z1;
        }
        __syncthreads();
        mfma_tile(As, Bs, wm, wn, l, acc);
        __syncthreads();
    }
    // epilogue: run-compressed segment-max (sorted dst -> few flushes)
#pragma unroll
    for (int mt = 0; mt < 4; ++mt) {
        int base = wm + mt * 16 + (l >> 4) * 4;
        int d0 = sdst[base], d1 = sdst[base + 1], d2 = sdst[base + 2], d3 = sdst[base + 3];
#pragma unroll
        for (int nt = 0; nt < 4; ++nt) {
            int col = n0 + wn + nt * 16 + (l & 15);
            f32x4 a = acc[mt][nt];
            float m = a[0];
            if (d1 == d0) m = fmaxf(m, a[1]); else { kflush(K, d0, col, m); m = a[1]; }
            if (d2 == d1) m = fmaxf(m, a[2]); else { kflush(K, d1, col, m); m = a[2]; }
            if (d3 == d2) m = fmaxf(m, a[3]); else { kflush(K, d2, col, m); m = a[3]; }
            kflush(K, d3, col, m);
        }
    }
}

// ================= decode keys -> h bf16 =================
__global__ __launch_bounds__(256) void decode_kernel(
    const unsigned int* __restrict__ K, const float* __restrict__ b2,
    short* __restrict__ hb) {
    int idx = blockIdx.x * 256 + threadIdx.x;
    unsigned int k = K[idx];
    int c = idx & (HDIM - 1);
    float v = 0.f;
    if (k != 0u) {
        unsigned int b = (k & 0x80000000u) ? (k ^ 0x80000000u) : ~k;
        v = __uint_as_float(b) + b2[c];
    }
    hb[idx] = (short)f2b(fmaxf(v, 0.f));
}

// ================= gather (bf16) =================
__global__ __launch_bounds__(256) void gather_bf16_kernel(
    const short* __restrict__ hb, const int* __restrict__ sel,
    short* __restrict__ hgb) {
    int idx = blockIdx.x * 256 + threadIdx.x;          // 4096 rows x 64 chunks
    int row = idx >> 6, c = idx & 63;
    int b = row >> 9;                                  // SEL = 512
    int s = sel[row];
    ((uint4*)hgb)[idx] = ((const uint4*)(hb + (((size_t)(b * SEQ + s)) << 9)))[c];
}

// ================= generic MFMA GEMM (FFN), bf16 in, bf16 or fp32 out =================
__global__ __launch_bounds__(256) void ffn_gemm_kernel(
    const short* __restrict__ A, const short* __restrict__ Wt,
    const float* __restrict__ bias, short* __restrict__ Cb,
    float* __restrict__ Cf, int relu) {
    __shared__ short As[128 * 32];
    __shared__ short Bs[128 * 32];
    const int t = threadIdx.x;
    const int m0 = blockIdx.x * 128, n0 = blockIdx.y * 128;
    const int w = t >> 6, l = t & 63;
    const int wm = (w & 1) * 64, wn = (w >> 1) * 64;
    f32x4 acc[4][4] = {};
    for (int kc = 0; kc < HDIM; kc += 32) {
        stage_tile(A + (size_t)m0 * HDIM, kc, As, t);
        stage_tile(Wt + (size_t)n0 * HDIM, kc, Bs, t);
        __syncthreads();
        mfma_tile(As, Bs, wm, wn, l, acc);
        __syncthreads();
    }
#pragma unroll
    for (int mt = 0; mt < 4; ++mt) {
        int m = m0 + wm + mt * 16 + (l >> 4) * 4;
#pragma unroll
        for (int nt = 0; nt < 4; ++nt) {
            int n = n0 + wn + nt * 16 + (l & 15);
            float bv = bias[n];
#pragma unroll
            for (int r = 0; r < 4; ++r) {
                float v = acc[mt][nt][r] + bv;
                if (relu) v = fmaxf(v, 0.f);
                if (Cf) Cf[(size_t)(m + r) * HDIM + n] = v;
                else    Cb[(size_t)(m + r) * HDIM + n] = (short)f2b(v);
            }
        }
    }
}

extern "C" void kernel_launch(void* const* d_in, const int* in_sizes, int n_in,
                              void* d_out, int out_size, void* d_ws, size_t ws_size,
                              hipStream_t stream) {
    const float* x   = (const float*)d_in[0];
    const int*   ei  = (const int*)d_in[1];
    const int*   sel = (const int*)d_in[2];
    const int*   src = ei;
    const int*   dst = ei + EDGES;
    const float* cw1[3] = {(const float*)d_in[4],  (const float*)d_in[8],  (const float*)d_in[12]};
    const float* cb1[3] = {(const float*)d_in[5],  (const float*)d_in[9],  (const float*)d_in[13]};
    const float* cw2[3] = {(const float*)d_in[6],  (const float*)d_in[10], (const float*)d_in[14]};
    const float* cb2[3] = {(const float*)d_in[7],  (const float*)d_in[11], (const float*)d_in[15]};
    const float* fw1 = (const float*)d_in[16];
    const float* fb1 = (const float*)d_in[17];
    const float* fw2 = (const float*)d_in[18];
    const float* fb2 = (const float*)d_in[19];
    float* out = (float*)d_out;

    const size_t MB = 1024 * 1024;
    char* p = (char*)d_ws;
    unsigned int* keys = (unsigned int*)p;                   // 32 MB
    short* U    = (short*)(p + 32 * MB);                     // 16 MB
    short* V    = (short*)(p + 48 * MB);                     // 16 MB
    short* hb   = (short*)(p + 64 * MB);                     // 16 MB
    short* WdT  = (short*)(p + 80 * MB);                     // 0.5 MB each
    short* w1bT = WdT + 512 * 512;
    short* W2T  = w1bT + 512 * 512;
    short* fw1T = W2T + 512 * 512;
    short* fw2T = fw1T + 512 * 512;
    int*   dstS = (int*)(p + 83 * MB);                       // 1 MB
    int*   srcS = (int*)(p + 84 * MB);                       // 1 MB
    int*   hist = (int*)(p + 85 * MB);                       // 64 KB
    int*   curs = hist + N_NODES;                            // 64 KB
    short* hgb  = (short*)(p + 86 * MB);                     // 4 MB
    short* t1b  = (short*)(p + 90 * MB);                     // 4 MB

    // --- sort edges by dst (edges constant across layers) ---
    hipMemsetAsync(hist, 0, N_NODES * sizeof(int), stream);
    hist_kernel<<<EDGES / 256, 256, 0, stream>>>(dst, hist);
    scan_kernel<<<1, 256, 0, stream>>>(hist, curs);
    scatter_kernel<<<EDGES / 256, 256, 0, stream>>>(dst, src, curs, dstS, srcS);

    cvt_bf16_kernel<<<8192, 256, 0, stream>>>(x, hb);
    tr_kernel<<<dim3(16, 16, 2), dim3(32, 8), 0, stream>>>(fw1, fw2, fw1T, fw2T);

    for (int l = 0; l < 3; ++l) {
        prep_weights_kernel<<<dim3(16, 16, 3), dim3(32, 8), 0, stream>>>(
            cw1[l], cw2[l], WdT, w1bT, W2T);
        node_gemm_uv_kernel<<<dim3(128, 8), 256, 0, stream>>>(hb, WdT, w1bT, cb1[l], U, V);
        hipMemsetAsync(keys, 0, 32 * MB, stream);
        edge_mfma_kernel<<<dim3(2048, 4), 256, 0, stream>>>(U, V, W2T, srcS, dstS, keys);
        decode_kernel<<<(N_NODES * HDIM) / 256, 256, 0, stream>>>(keys, cb2[l], hb);
    }

    gather_bf16_kernel<<<(4096 * 64) / 256, 256, 0, stream>>>(hb, sel, hgb);
    ffn_gemm_kernel<<<dim3(32, 4), 256, 0, stream>>>(hgb, fw1T, fb1, t1b, nullptr, 1);
    ffn_gemm_kernel<<<dim3(32, 4), 256, 0, stream>>>(t1b, fw2T, fb2, nullptr, out, 0);
}

// Round 5
// 1441.084 us; speedup vs baseline: 7.5522x; 1.0350x over previous
//
#include <hip/hip_runtime.h>
#include <hip/hip_bf16.h>

// UCCAEncoder: 3x EdgeConv(max) + FFN + gather. R4b (R4 with compile fix):
//  - z path on fp16: U,V stored fp16, W2^T fp16; A-tile pack is native
//    _Float16 ext-vector add + __builtin_elementwise_max (v_pk_add_f16 +
//    v_pk_max_f16), edge GEMM uses mfma_f32_16x16x32_f16.
//  - else unchanged from R3 (sorted edges, fused U/V node GEMM,
//    run-compressed atomicMax segment-max, bf16 h path, MFMA FFN).

#define N_NODES 16384
#define EDGES   262144
#define HDIM    512
#define SEQ     2048

typedef __attribute__((ext_vector_type(8))) short short8;
typedef __attribute__((ext_vector_type(8))) _Float16 half8;
typedef __attribute__((ext_vector_type(2))) _Float16 half2v;
typedef __attribute__((ext_vector_type(4))) float f32x4;

__device__ __forceinline__ void gld16(const void* g, void* l) {
    __builtin_amdgcn_global_load_lds(
        (const __attribute__((address_space(1))) void*)g,
        (__attribute__((address_space(3))) void*)l, 16, 0, 0);
}
__device__ __forceinline__ unsigned short f2b(float f) {   // fp32 -> bf16 RNE
    unsigned int x = __float_as_uint(f);
    return (unsigned short)((x + 0x7fffu + ((x >> 16) & 1u)) >> 16);
}
__device__ __forceinline__ unsigned short f2h(float f) {   // fp32 -> fp16 bits
    _Float16 h = (_Float16)f;
    return __builtin_bit_cast(unsigned short, h);
}
// packed fp16: z = max(u+v, 0) on 2 lanes in one uint (v_pk_add_f16 + v_pk_max_f16)
__device__ __forceinline__ unsigned int zpack_h(unsigned int u, unsigned int v) {
    half2v a = __builtin_bit_cast(half2v, u);
    half2v b = __builtin_bit_cast(half2v, v);
    half2v s = a + b;
    half2v z = {(_Float16)0.f, (_Float16)0.f};
    half2v r = __builtin_elementwise_max(s, z);
    return __builtin_bit_cast(unsigned int, r);
}
// LDS k-seg swizzle: physical slot = logical_seg ^ ((row>>1)&3)
__device__ __forceinline__ short8 frag_ld(const short* S, int row, int q) {
    int p = q ^ ((row >> 1) & 3);
    return *(const short8*)(S + row * 32 + p * 8);
}
__device__ __forceinline__ half8 frag_ldh(const short* S, int row, int q) {
    int p = q ^ ((row >> 1) & 3);
    return *(const half8*)(S + row * 32 + p * 8);
}
// stage 128 rows x 32 k (16-bit elems) via global_load_lds, swizzled slots
__device__ __forceinline__ void stage_tile(const short* G, int kc, short* S, int t) {
#pragma unroll
    for (int it = 0; it < 2; ++it) {
        int lin = it * 256 + t;
        int row = lin >> 2, p = lin & 3;
        int q = p ^ ((row >> 1) & 3);
        gld16(G + (size_t)row * HDIM + kc + q * 8, S + lin * 8);
    }
}
__device__ __forceinline__ void mfma_tile_bf16(const short* As, const short* Bs,
                                               int wm, int wn, int l, f32x4 acc[4][4]) {
    short8 a[4], b[4];
#pragma unroll
    for (int mt = 0; mt < 4; ++mt) a[mt] = frag_ld(As, wm + mt * 16 + (l & 15), l >> 4);
#pragma unroll
    for (int nt = 0; nt < 4; ++nt) b[nt] = frag_ld(Bs, wn + nt * 16 + (l & 15), l >> 4);
#pragma unroll
    for (int mt = 0; mt < 4; ++mt)
#pragma unroll
        for (int nt = 0; nt < 4; ++nt)
            acc[mt][nt] = __builtin_amdgcn_mfma_f32_16x16x32_bf16(a[mt], b[nt], acc[mt][nt], 0, 0, 0);
}
__device__ __forceinline__ void mfma_tile_f16(const short* As, const short* Bs,
                                              int wm, int wn, int l, f32x4 acc[4][4]) {
    half8 a[4], b[4];
#pragma unroll
    for (int mt = 0; mt < 4; ++mt) a[mt] = frag_ldh(As, wm + mt * 16 + (l & 15), l >> 4);
#pragma unroll
    for (int nt = 0; nt < 4; ++nt) b[nt] = frag_ldh(Bs, wn + nt * 16 + (l & 15), l >> 4);
#pragma unroll
    for (int mt = 0; mt < 4; ++mt)
#pragma unroll
        for (int nt = 0; nt < 4; ++nt)
            acc[mt][nt] = __builtin_amdgcn_mfma_f32_16x16x32_f16(a[mt], b[nt], acc[mt][nt], 0, 0, 0);
}

// ================= edge sort (counting sort by dst) =================
__global__ __launch_bounds__(256) void hist_kernel(
    const int* __restrict__ dst, int* __restrict__ hist) {
    int idx = blockIdx.x * 256 + threadIdx.x;
    atomicAdd(&hist[dst[idx]], 1);
}
__global__ __launch_bounds__(256) void scan_kernel(
    const int* __restrict__ hist, int* __restrict__ cursor) {
    __shared__ int part[256];
    const int t = threadIdx.x, base = t * 64;
    int sum = 0;
    for (int i = 0; i < 64; ++i) sum += hist[base + i];
    part[t] = sum;
    __syncthreads();
    int run = 0;
    for (int i = 0; i < t; ++i) run += part[i];
    for (int i = 0; i < 64; ++i) {
        int h = hist[base + i];
        cursor[base + i] = run;
        run += h;
    }
}
__global__ __launch_bounds__(256) void scatter_kernel(
    const int* __restrict__ dst, const int* __restrict__ src,
    int* __restrict__ cursor, int* __restrict__ dstS, int* __restrict__ srcS) {
    int idx = blockIdx.x * 256 + threadIdx.x;
    int d = dst[idx];
    int p = atomicAdd(&cursor[d], 1);
    dstS[p] = d;
    srcS[p] = src[idx];
}

// ================= weights / input prep =================
// conv trio -> [n][k]: z=0 Wd=w1a-w1b (bf16), z=1 w1b (bf16), z=2 w2 (fp16)
__global__ __launch_bounds__(256) void prep_weights_kernel(
    const float* __restrict__ w1, const float* __restrict__ w2,
    short* __restrict__ WdT, short* __restrict__ w1bT, short* __restrict__ W2T) {
    __shared__ float tile[32][33];
    const int which = blockIdx.z;
    const int k0 = blockIdx.x * 32, n0 = blockIdx.y * 32;
    const int tx = threadIdx.x, ty = threadIdx.y;
#pragma unroll
    for (int i = 0; i < 4; ++i) {
        int k = k0 + ty + i * 8, n = n0 + tx;
        float v;
        if (which == 0)      v = w1[k * 512 + n] - w1[(k + 512) * 512 + n];
        else if (which == 1) v = w1[(k + 512) * 512 + n];
        else                 v = w2[k * 512 + n];
        tile[ty + i * 8][tx] = v;
    }
    __syncthreads();
    short* out = which == 0 ? WdT : (which == 1 ? w1bT : W2T);
#pragma unroll
    for (int i = 0; i < 4; ++i) {
        int n = n0 + ty + i * 8, k = k0 + tx;
        float v = tile[tx][ty + i * 8];
        out[(size_t)n * 512 + k] = (short)(which == 2 ? f2h(v) : f2b(v));
    }
}
// FFN mats (bf16): z=0 fw1, z=1 fw2
__global__ __launch_bounds__(256) void tr_kernel(
    const float* __restrict__ W1, const float* __restrict__ W2,
    short* __restrict__ T1, short* __restrict__ T2) {
    __shared__ float tile[32][33];
    const float* W = blockIdx.z ? W2 : W1;
    short* T = blockIdx.z ? T2 : T1;
    const int k0 = blockIdx.x * 32, n0 = blockIdx.y * 32;
    const int tx = threadIdx.x, ty = threadIdx.y;
#pragma unroll
    for (int i = 0; i < 4; ++i)
        tile[ty + i * 8][tx] = W[(k0 + ty + i * 8) * 512 + n0 + tx];
    __syncthreads();
#pragma unroll
    for (int i = 0; i < 4; ++i)
        T[(size_t)(n0 + ty + i * 8) * 512 + k0 + tx] = (short)f2b(tile[tx][ty + i * 8]);
}
__global__ __launch_bounds__(256) void cvt_bf16_kernel(
    const float* __restrict__ x, short* __restrict__ xb) {
    int idx = blockIdx.x * 256 + threadIdx.x;
    float4 v = ((const float4*)x)[idx];
    uint2 o;
    o.x = (unsigned int)f2b(v.x) | ((unsigned int)f2b(v.y) << 16);
    o.y = (unsigned int)f2b(v.z) | ((unsigned int)f2b(v.w) << 16);
    ((uint2*)xb)[idx] = o;
}

// ================= fused U/V node GEMM (bf16 in, fp16 out) =================
// grid (128, 8): y<4 -> U = h@WdT^T + b1 ; y>=4 -> V = h@w1bT^T
__global__ __launch_bounds__(256) void node_gemm_uv_kernel(
    const short* __restrict__ A, const short* __restrict__ WdT,
    const short* __restrict__ w1bT, const float* __restrict__ b1,
    short* __restrict__ U, short* __restrict__ V) {
    __shared__ short As[128 * 32];
    __shared__ short Bs[128 * 32];
    const int t = threadIdx.x;
    const int by = blockIdx.y;
    const short* Wt = (by < 4) ? WdT : w1bT;
    short* C = (by < 4) ? U : V;
    const float* bias = (by < 4) ? b1 : nullptr;
    const int m0 = blockIdx.x * 128, n0 = (by & 3) * 128;
    const int w = t >> 6, l = t & 63;
    const int wm = (w & 1) * 64, wn = (w >> 1) * 64;
    f32x4 acc[4][4] = {};
    for (int kc = 0; kc < HDIM; kc += 32) {
        stage_tile(A + (size_t)m0 * HDIM, kc, As, t);
        stage_tile(Wt + (size_t)n0 * HDIM, kc, Bs, t);
        __syncthreads();
        mfma_tile_bf16(As, Bs, wm, wn, l, acc);
        __syncthreads();
    }
#pragma unroll
    for (int mt = 0; mt < 4; ++mt) {
        int m = m0 + wm + mt * 16 + (l >> 4) * 4;
#pragma unroll
        for (int nt = 0; nt < 4; ++nt) {
            int n = n0 + wn + nt * 16 + (l & 15);
            float bv = bias ? bias[n] : 0.f;
#pragma unroll
            for (int r = 0; r < 4; ++r)
                C[(size_t)(m + r) * HDIM + n] = (short)f2h(acc[mt][nt][r] + bv);
        }
    }
}

// ================= edge GEMM (sorted, fp16) + fused segment-max =================
__device__ __forceinline__ void kflush(unsigned int* K, int d, int col, float m) {
    unsigned int b = __float_as_uint(m);
    unsigned int key = ((int)b < 0) ? ~b : (b | 0x80000000u);
    atomicMax(K + (((size_t)d) << 9) + col, key);
}
__global__ __launch_bounds__(256) void edge_mfma_kernel(
    const short* __restrict__ U, const short* __restrict__ V,
    const short* __restrict__ Wt, const int* __restrict__ srcS,
    const int* __restrict__ dstS, unsigned int* __restrict__ K) {
    __shared__ short As[128 * 32];
    __shared__ short Bs[128 * 32];
    __shared__ int sdst[128], ssrc[128];
    const int t = threadIdx.x;
    const int e0 = blockIdx.x * 128, n0 = blockIdx.y * 128;
    if (t < 128) { sdst[t] = dstS[e0 + t]; ssrc[t] = srcS[e0 + t]; }
    __syncthreads();
    const int w = t >> 6, l = t & 63;
    const int wm = (w & 1) * 64, wn = (w >> 1) * 64;
    const int arow = t >> 1, ahalf = t & 1;
    const short* up = U + (((size_t)sdst[arow]) << 9) + ahalf * 16;
    const short* vp = V + (((size_t)ssrc[arow]) << 9) + ahalf * 16;
    const int f = (arow >> 1) & 3;
    unsigned int* As_u = (unsigned int*)As;
    f32x4 acc[4][4] = {};

    for (int kc = 0; kc < HDIM; kc += 32) {
        stage_tile(Wt + (size_t)n0 * HDIM, kc, Bs, t);
        {   // A tile: gather 16 fp16 of U,V -> pk_add + pk_max -> LDS (swizzled)
            const uint4 u0 = *(const uint4*)(up + kc);
            const uint4 u1 = *(const uint4*)(up + kc + 8);
            const uint4 v0 = *(const uint4*)(vp + kc);
            const uint4 v1 = *(const uint4*)(vp + kc + 8);
            uint4 z0, z1;
            z0.x = zpack_h(u0.x, v0.x); z0.y = zpack_h(u0.y, v0.y);
            z0.z = zpack_h(u0.z, v0.z); z0.w = zpack_h(u0.w, v0.w);
            z1.x = zpack_h(u1.x, v1.x); z1.y = zpack_h(u1.y, v1.y);
            z1.z = zpack_h(u1.z, v1.z); z1.w = zpack_h(u1.w, v1.w);
            int p0 = (2 * ahalf) ^ f, p1 = (2 * ahalf + 1) ^ f;
            *(uint4*)(As_u + arow * 16 + p0 * 4) = z0;
            *(uint4*)(As_u + arow * 16 + p1 * 4) = z1;
        }
        __syncthreads();
        mfma_tile_f16(As, Bs, wm, wn, l, acc);
        __syncthreads();
    }
    // epilogue: run-compressed segment-max (sorted dst -> few flushes)
#pragma unroll
    for (int mt = 0; mt < 4; ++mt) {
        int base = wm + mt * 16 + (l >> 4) * 4;
        int d0 = sdst[base], d1 = sdst[base + 1], d2 = sdst[base + 2], d3 = sdst[base + 3];
#pragma unroll
        for (int nt = 0; nt < 4; ++nt) {
            int col = n0 + wn + nt * 16 + (l & 15);
            f32x4 a = acc[mt][nt];
            float m = a[0];
            if (d1 == d0) m = fmaxf(m, a[1]); else { kflush(K, d0, col, m); m = a[1]; }
            if (d2 == d1) m = fmaxf(m, a[2]); else { kflush(K, d1, col, m); m = a[2]; }
            if (d3 == d2) m = fmaxf(m, a[3]); else { kflush(K, d2, col, m); m = a[3]; }
            kflush(K, d3, col, m);
        }
    }
}

// ================= decode keys -> h bf16 =================
__global__ __launch_bounds__(256) void decode_kernel(
    const unsigned int* __restrict__ K, const float* __restrict__ b2,
    short* __restrict__ hb) {
    int idx = blockIdx.x * 256 + threadIdx.x;
    unsigned int k = K[idx];
    int c = idx & (HDIM - 1);
    float v = 0.f;
    if (k != 0u) {
        unsigned int b = (k & 0x80000000u) ? (k ^ 0x80000000u) : ~k;
        v = __uint_as_float(b) + b2[c];
    }
    hb[idx] = (short)f2b(fmaxf(v, 0.f));
}

// ================= gather (bf16) =================
__global__ __launch_bounds__(256) void gather_bf16_kernel(
    const short* __restrict__ hb, const int* __restrict__ sel,
    short* __restrict__ hgb) {
    int idx = blockIdx.x * 256 + threadIdx.x;          // 4096 rows x 64 chunks
    int row = idx >> 6, c = idx & 63;
    int b = row >> 9;                                  // SEL = 512
    int s = sel[row];
    ((uint4*)hgb)[idx] = ((const uint4*)(hb + (((size_t)(b * SEQ + s)) << 9)))[c];
}

// ================= MFMA GEMM (FFN), bf16 in, bf16 or fp32 out =================
__global__ __launch_bounds__(256) void ffn_gemm_kernel(
    const short* __restrict__ A, const short* __restrict__ Wt,
    const float* __restrict__ bias, short* __restrict__ Cb,
    float* __restrict__ Cf, int relu) {
    __shared__ short As[128 * 32];
    __shared__ short Bs[128 * 32];
    const int t = threadIdx.x;
    const int m0 = blockIdx.x * 128, n0 = blockIdx.y * 128;
    const int w = t >> 6, l = t & 63;
    const int wm = (w & 1) * 64, wn = (w >> 1) * 64;
    f32x4 acc[4][4] = {};
    for (int kc = 0; kc < HDIM; kc += 32) {
        stage_tile(A + (size_t)m0 * HDIM, kc, As, t);
        stage_tile(Wt + (size_t)n0 * HDIM, kc, Bs, t);
        __syncthreads();
        mfma_tile_bf16(As, Bs, wm, wn, l, acc);
        __syncthreads();
    }
#pragma unroll
    for (int mt = 0; mt < 4; ++mt) {
        int m = m0 + wm + mt * 16 + (l >> 4) * 4;
#pragma unroll
        for (int nt = 0; nt < 4; ++nt) {
            int n = n0 + wn + nt * 16 + (l & 15);
            float bv = bias[n];
#pragma unroll
            for (int r = 0; r < 4; ++r) {
                float v = acc[mt][nt][r] + bv;
                if (relu) v = fmaxf(v, 0.f);
                if (Cf) Cf[(size_t)(m + r) * HDIM + n] = v;
                else    Cb[(size_t)(m + r) * HDIM + n] = (short)f2b(v);
            }
        }
    }
}

extern "C" void kernel_launch(void* const* d_in, const int* in_sizes, int n_in,
                              void* d_out, int out_size, void* d_ws, size_t ws_size,
                              hipStream_t stream) {
    const float* x   = (const float*)d_in[0];
    const int*   ei  = (const int*)d_in[1];
    const int*   sel = (const int*)d_in[2];
    const int*   src = ei;
    const int*   dst = ei + EDGES;
    const float* cw1[3] = {(const float*)d_in[4],  (const float*)d_in[8],  (const float*)d_in[12]};
    const float* cb1[3] = {(const float*)d_in[5],  (const float*)d_in[9],  (const float*)d_in[13]};
    const float* cw2[3] = {(const float*)d_in[6],  (const float*)d_in[10], (const float*)d_in[14]};
    const float* cb2[3] = {(const float*)d_in[7],  (const float*)d_in[11], (const float*)d_in[15]};
    const float* fw1 = (const float*)d_in[16];
    const float* fb1 = (const float*)d_in[17];
    const float* fw2 = (const float*)d_in[18];
    const float* fb2 = (const float*)d_in[19];
    float* out = (float*)d_out;

    const size_t MB = 1024 * 1024;
    char* p = (char*)d_ws;
    unsigned int* keys = (unsigned int*)p;                   // 32 MB
    short* U    = (short*)(p + 32 * MB);                     // 16 MB (fp16)
    short* V    = (short*)(p + 48 * MB);                     // 16 MB (fp16)
    short* hb   = (short*)(p + 64 * MB);                     // 16 MB (bf16)
    short* WdT  = (short*)(p + 80 * MB);                     // 0.5 MB each
    short* w1bT = WdT + 512 * 512;
    short* W2T  = w1bT + 512 * 512;                          // fp16
    short* fw1T = W2T + 512 * 512;
    short* fw2T = fw1T + 512 * 512;
    int*   dstS = (int*)(p + 83 * MB);                       // 1 MB
    int*   srcS = (int*)(p + 84 * MB);                       // 1 MB
    int*   hist = (int*)(p + 85 * MB);                       // 64 KB
    int*   curs = hist + N_NODES;                            // 64 KB
    short* hgb  = (short*)(p + 86 * MB);                     // 4 MB
    short* t1b  = (short*)(p + 90 * MB);                     // 4 MB

    // --- sort edges by dst (edges constant across layers) ---
    (void)hipMemsetAsync(hist, 0, N_NODES * sizeof(int), stream);
    hist_kernel<<<EDGES / 256, 256, 0, stream>>>(dst, hist);
    scan_kernel<<<1, 256, 0, stream>>>(hist, curs);
    scatter_kernel<<<EDGES / 256, 256, 0, stream>>>(dst, src, curs, dstS, srcS);

    cvt_bf16_kernel<<<8192, 256, 0, stream>>>(x, hb);
    tr_kernel<<<dim3(16, 16, 2), dim3(32, 8), 0, stream>>>(fw1, fw2, fw1T, fw2T);

    for (int l = 0; l < 3; ++l) {
        prep_weights_kernel<<<dim3(16, 16, 3), dim3(32, 8), 0, stream>>>(
            cw1[l], cw2[l], WdT, w1bT, W2T);
        node_gemm_uv_kernel<<<dim3(128, 8), 256, 0, stream>>>(hb, WdT, w1bT, cb1[l], U, V);
        (void)hipMemsetAsync(keys, 0, 32 * MB, stream);
        edge_mfma_kernel<<<dim3(2048, 4), 256, 0, stream>>>(U, V, W2T, srcS, dstS, keys);
        decode_kernel<<<(N_NODES * HDIM) / 256, 256, 0, stream>>>(keys, cb2[l], hb);
    }

    gather_bf16_kernel<<<(4096 * 64) / 256, 256, 0, stream>>>(hb, sel, hgb);
    ffn_gemm_kernel<<<dim3(32, 4), 256, 0, stream>>>(hgb, fw1T, fb1, t1b, nullptr, 1);
    ffn_gemm_kernel<<<dim3(32, 4), 256, 0, stream>>>(t1b, fw2T, fb2, nullptr, out, 0);
}